// Round 14
// baseline (200.927 us; speedup 1.0000x reference)
//
#include <hip/hip_runtime.h>
#include <stdint.h>

// Workspace byte offsets
#define OFF_W1  0        // 1024*32 u32 packed sign bits, channel-major (fallback)
#define OFF_W2  131072
#define OFF_W3  262144
#define OFF_WFC 393216   // 10*32 u32 (fallback FC)
#define OFF_T1  395264   // 1024 int32 popcount thresholds (fallback)
#define OFF_T2  399360
#define OFF_T3  403456
#define OFF_SFC 407552   // double: mean|wfc|
// MFMA: fragment-ordered i8 weight files. Layout per layer:
//   frag[(nt*16 + kt)*1024 + lane*16 + e], nt=ch>>4 (64), kt=k>>6 (16),
//   lane = (ch&15) | (((k>>4)&3)<<4), e = k&15.  1 MB per layer.
#define OFF_F1  409600
#define OFF_F2  1458176
#define OFF_F3  2506752
#define OFF_FFC 3555328  // 16 KB: wfc frags (16 cols: 10 real + 6 don't-care)
#define OFF_C1  3571712  // 1024 int32 dot-form thresholds (act = dot >= Cdot)
#define OFF_C2  3575808
#define OFF_C3  3579904
// Two 8 MB i8 activation buffers [8192][1024], plain row-major.
#define OFF_S0  3584000
#define OFF_S1  11972608
#define WS_NEED_V12 20361216u
#define RWS 16           // rows per block in fallback fused kernel

typedef int int4v __attribute__((ext_vector_type(4)));

// ---------------------------------------------------------------------------
// Prep — 385 blocks (x-pack folded into layer-1 in R14):
//   blocks 0..383: W bitpack (fallback) + i8 frag file + thresholds (Td, Cdot)
//   block 384: wfc (both forms) + mean|wfc|.
// ---------------------------------------------------------------------------
__global__ __launch_bounds__(256) void bnn_prep(
    const float* __restrict__ w1, const float* __restrict__ b1, const float* __restrict__ g1,
    const float* __restrict__ be1, const float* __restrict__ m1, const float* __restrict__ v1,
    const float* __restrict__ w2, const float* __restrict__ b2, const float* __restrict__ g2,
    const float* __restrict__ be2, const float* __restrict__ m2, const float* __restrict__ v2,
    const float* __restrict__ w3, const float* __restrict__ b3, const float* __restrict__ g3,
    const float* __restrict__ be3, const float* __restrict__ m3, const float* __restrict__ v3,
    const float* __restrict__ wfc,
    uint32_t* __restrict__ ws)
{
    const int blk  = blockIdx.x;
    const int t    = threadIdx.x;
    const int lane = t & 63;
    const int wv   = t >> 6;

    if (blk < 384) {
        const int gid = blk * 256 + t;      // 0..98303
        const int l   = gid >> 15;          // layer 0..2 (32768 words each)
        const int rem = gid & 32767;
        const int o   = rem >> 5;           // channel
        const int k32 = rem & 31;           // word within channel
        const float *w, *bb, *g, *be, *m, *v;
        int K; uint32_t *Wp, *Fl; int *T, *Cdl;
        if (l == 0)      { w=w1; bb=b1; g=g1; be=be1; m=m1; v=v1; K=784;
                           Wp = ws + OFF_W1/4; Fl = ws + OFF_F1/4;
                           T = (int*)(ws + OFF_T1/4); Cdl = (int*)(ws + OFF_C1/4); }
        else if (l == 1) { w=w2; bb=b2; g=g2; be=be2; m=m2; v=v2; K=1024;
                           Wp = ws + OFF_W2/4; Fl = ws + OFF_F2/4;
                           T = (int*)(ws + OFF_T2/4); Cdl = (int*)(ws + OFF_C2/4); }
        else             { w=w3; bb=b3; g=g3; be=be3; m=m3; v=v3; K=1024;
                           Wp = ws + OFF_W3/4; Fl = ws + OFF_F3/4;
                           T = (int*)(ws + OFF_T3/4); Cdl = (int*)(ws + OFF_C3/4); }

        const int base = 32 * k32;
        uint32_t bits = 0;
        double s = 0.0;
        if (base < K) {
            const float4* p = (const float4*)(w + (size_t)o * K + base);
            const int n4 = (K - base >= 32) ? 8 : 4;   // K=784, k32=24 -> 16 elems
            for (int i = 0; i < n4; ++i) {
                float4 q = p[i];
                bits |= (q.x >= 0.0f) ? (1u << (4*i + 0)) : 0u;
                bits |= (q.y >= 0.0f) ? (1u << (4*i + 1)) : 0u;
                bits |= (q.z >= 0.0f) ? (1u << (4*i + 2)) : 0u;
                bits |= (q.w >= 0.0f) ? (1u << (4*i + 3)) : 0u;
                s += fabs((double)q.x) + fabs((double)q.y)
                   + fabs((double)q.z) + fabs((double)q.w);
            }
        }
        // half-wave (32-lane) xor tree: all lanes of the half get channel sum
        #pragma unroll
        for (int mask = 1; mask <= 16; mask <<= 1)
            s += __shfl_xor(s, mask, 64);
        if (k32 == 0) {
            double scale = s / (double)K;                        // mean|w| > 0
            double r = (double)g[o] / sqrt((double)v[o] + 1e-5); // > 0
            double tt = (((double)m[o] - (double)bb[o]) * r - (double)be[o]) / (scale * r);
            double C  = ceil(tt);                                // act=+1 iff dot >= C
            double Cc = fmax(fmin(C, 100000.0), -100000.0);
            Cdl[o] = (int)Cc;
            double Td = floor(((double)K - C) * 0.5);
            Td = fmax(fmin(Td, 100000.0), -1.0);
            T[o] = (int)Td;
        }
        Wp[(size_t)o * 32 + k32] = bits;                          // bitpacked

        // i8 fragment bytes: 32 bits -> two 16-byte groups in frag order.
        const int nt = o >> 4;
        #pragma unroll
        for (int g2i = 0; g2i < 2; ++g2i) {
            const int kg = base + g2i * 16;
            const int kt = kg >> 6;
            const int lane16 = (o & 15) | (((kg >> 4) & 3) << 4);
            uint32_t fb[4];
            #pragma unroll
            for (int wd = 0; wd < 4; ++wd) {
                uint32_t vv = 0;
                #pragma unroll
                for (int bj = 0; bj < 4; ++bj) {
                    const int idx = g2i*16 + wd*4 + bj;
                    const int kk  = base + idx;
                    uint32_t byte = (kk < K) ? (((bits >> idx) & 1u) ? 0x01u : 0xFFu) : 0x00u;
                    vv |= byte << (8*bj);
                }
                fb[wd] = vv;
            }
            uint32_t* dst = Fl + (size_t)((nt*16 + kt) * 256 + lane16 * 4);
            *(uint4*)dst = *(uint4*)fb;
        }
    } else {
        // wfc: 320 words (10 ch x 32); thread t does word t and (t<64) t+256
        uint32_t* Wp  = ws + OFF_WFC/4;
        uint32_t* Ffc = ws + OFF_FFC/4;
        double s = 0.0;
        #pragma unroll
        for (int part = 0; part < 2; ++part) {
            const int tt_ = t + part * 256;
            if (part == 1 && t >= 64) break;
            const int o = tt_ >> 5, k32 = tt_ & 31;
            const int base = 32 * k32;
            const float4* p = (const float4*)(wfc + o * 1024 + base);
            uint32_t bits = 0;
            #pragma unroll
            for (int i = 0; i < 8; ++i) {
                float4 q = p[i];
                bits |= (q.x >= 0.0f) ? (1u << (4*i + 0)) : 0u;
                bits |= (q.y >= 0.0f) ? (1u << (4*i + 1)) : 0u;
                bits |= (q.z >= 0.0f) ? (1u << (4*i + 2)) : 0u;
                bits |= (q.w >= 0.0f) ? (1u << (4*i + 3)) : 0u;
                s += fabs((double)q.x) + fabs((double)q.y)
                   + fabs((double)q.z) + fabs((double)q.w);
            }
            Wp[tt_] = bits;
            #pragma unroll
            for (int g2i = 0; g2i < 2; ++g2i) {
                const int kg = base + g2i * 16;
                const int kt = kg >> 6;
                const int lane16 = (o & 15) | (((kg >> 4) & 3) << 4);
                uint32_t fb[4];
                #pragma unroll
                for (int wd = 0; wd < 4; ++wd) {
                    uint32_t vv = 0;
                    #pragma unroll
                    for (int bj = 0; bj < 4; ++bj) {
                        const int idx = g2i*16 + wd*4 + bj;
                        vv |= (((bits >> idx) & 1u) ? 0x01u : 0xFFu) << (8*bj);
                    }
                    fb[wd] = vv;
                }
                *(uint4*)(Ffc + (size_t)(kt * 256 + lane16 * 4)) = *(uint4*)fb;
            }
        }
        __shared__ double red[4];
        #pragma unroll
        for (int off = 32; off > 0; off >>= 1) s += __shfl_down(s, off, 64);
        if (lane == 0) red[wv] = s;
        __syncthreads();
        if (t == 0)
            *(double*)(ws + OFF_SFC/4) = (red[0] + red[1] + red[2] + red[3]) / 10240.0;
    }
}

// ---------------------------------------------------------------------------
// v13 (R23): per-layer MFMA GEMM, BM=64 x BN=256, grid 512 (2 blocks/CU).
// R13 landed 163.7us (best); layers ~8-10us each vs ~5-6us per-CU floor
// (MFMA 4.3, LDS-A 5.1, L1-B 3.4 us/layer). R14 changes:
//   1. template<FIRST>: layer 1 stages straight from x (float4 -> i8 in the
//      LDS-stage loop) — kills prep's 2048-block x-pack and the 16 MB S0
//      round-trip.
//   2. B fragments via __builtin_nontemporal_load: each fragment is read
//      exactly once per block (no L1 reuse by construction) — nt bypasses
//      L1 allocation, streaming L2->reg.
// ---------------------------------------------------------------------------
template<bool FIRST>
__global__ __launch_bounds__(512) void bnn_layer_mfma(
    const float*   __restrict__ x,       // used when FIRST
    const uint8_t* __restrict__ actIn,   // used when !FIRST
    const uint8_t* __restrict__ Wfrag,   // 1 MB fragment file
    const int*     __restrict__ Cdot,    // 1024 thresholds
    uint8_t* __restrict__ actOut)        // [8192][1024] i8
{
    __shared__ uint8_t At[64 * 1024];
    const int t    = threadIdx.x;
    const int lane = t & 63;
    const int wv   = t >> 6;            // 0..7
    const int rg   = blockIdx.x >> 2;   // 0..127
    const int cg   = blockIdx.x & 3;    // 0..3
    const int row0 = rg * 64;

    if (FIRST) {
        // stage from x: 64 rows x 256 u32 words; word w<196 packs 4 floats,
        // else zero pad (784 = 4*196 exactly). Consecutive t -> consecutive
        // w -> coalesced float4 reads.
        #pragma unroll
        for (int i = 0; i < 32; ++i) {
            const int id  = t + i * 512;     // 0..16383
            const int row = id >> 8;         // 0..63
            const int w   = id & 255;        // u32 word in row
            uint32_t wval = 0;
            if (w < 196) {
                const float4 q = *(const float4*)(x + (size_t)(row0 + row) * 784 + 4 * w);
                wval  = ((q.x >= 0.5f) ? 0x01u : 0xFFu);
                wval |= ((q.y >= 0.5f) ? 0x01u : 0xFFu) << 8;
                wval |= ((q.z >= 0.5f) ? 0x01u : 0xFFu) << 16;
                wval |= ((q.w >= 0.5f) ? 0x01u : 0xFFu) << 24;
            }
            *(uint32_t*)(At + row * 1024 + ((4 * w) ^ ((row & 7) << 4))) = wval;
        }
    } else {
        // stage A tile (64 KB): 4096 16-B chunks, thread does 8, coalesced.
        #pragma unroll
        for (int i = 0; i < 8; ++i) {
            const int id  = t + i * 512;     // 0..4095
            const int row = id >> 6;
            const int ks  = id & 63;
            uint4 v = *(const uint4*)(actIn + (size_t)(row0 + row) * 1024 + ks * 16);
            *(uint4*)(At + row * 1024 + ((ks * 16) ^ ((row & 7) << 4))) = v;
        }
    }
    __syncthreads();

    const int col = lane & 15;
    const int lg  = lane >> 4;          // 0..3
    const int nq  = cg * 16 + wv * 2;   // first of this wave's 2 n-tiles (0..63)

    int4v acc[4][2];
    #pragma unroll
    for (int m = 0; m < 4; ++m)
        #pragma unroll
        for (int j = 0; j < 2; ++j)
            acc[m][j] = (int4v){0, 0, 0, 0};

    // B double buffer, 1 kt deep; nontemporal (B has zero L1 reuse).
    int4v bq[2][2];
    #pragma unroll
    for (int j = 0; j < 2; ++j)
        bq[0][j] = __builtin_nontemporal_load(
            (const int4v*)(Wfrag + ((size_t)((nq + j) * 16) << 10) + lane * 16));

    #pragma unroll
    for (int kt = 0; kt < 16; ++kt) {
        const int cb = kt & 1, nb = cb ^ 1;
        if (kt < 15) {
            #pragma unroll
            for (int j = 0; j < 2; ++j)
                bq[nb][j] = __builtin_nontemporal_load(
                    (const int4v*)(Wfrag + ((size_t)((nq + j) * 16 + kt + 1) << 10) + lane * 16));
        }
        const int k0 = kt * 64 + lg * 16;
        int4v a[4];
        #pragma unroll
        for (int m = 0; m < 4; ++m)
            a[m] = *(const int4v*)(At + (m * 16 + col) * 1024 + (k0 ^ ((col & 7) << 4)));
        #pragma unroll
        for (int m = 0; m < 4; ++m)
            #pragma unroll
            for (int j = 0; j < 2; ++j)
                acc[m][j] = __builtin_amdgcn_mfma_i32_16x16x64_i8(a[m], bq[cb][j], acc[m][j], 0, 0, 0);
    }

    // ---- epilogue: threshold -> i8 act bytes, plain row-major global store.
    #pragma unroll
    for (int j = 0; j < 2; ++j) {
        const int ch  = (nq + j) * 16 + col;
        const int thr = Cdot[ch];
        #pragma unroll
        for (int m = 0; m < 4; ++m) {
            #pragma unroll
            for (int reg = 0; reg < 4; ++reg) {
                const int row = row0 + m * 16 + lg * 4 + reg;
                actOut[(size_t)row * 1024 + ch] =
                    (acc[m][j][reg] >= thr) ? (uint8_t)0x01 : (uint8_t)0xFF;
            }
        }
    }
}

// ---------------------------------------------------------------------------
// FC: one wave per 32 rows; A fragments loaded straight from global (L2-hot).
// ---------------------------------------------------------------------------
__global__ __launch_bounds__(64) void bnn_fc_mfma(
    const uint8_t* __restrict__ actIn,
    const uint32_t* __restrict__ ws,
    const float* __restrict__ bfc,
    float* __restrict__ out)
{
    const int lane = threadIdx.x;
    const int col  = lane & 15;
    const int lg   = lane >> 4;
    const int row0 = blockIdx.x * 32;
    const uint8_t* Bf = (const uint8_t*)ws + OFF_FFC;

    int4v acc[2];
    acc[0] = (int4v){0, 0, 0, 0};
    acc[1] = (int4v){0, 0, 0, 0};

    #pragma unroll
    for (int kt = 0; kt < 16; ++kt) {
        int4v b = __builtin_nontemporal_load(
            (const int4v*)(Bf + ((size_t)kt << 10) + lane * 16));
        #pragma unroll
        for (int m = 0; m < 2; ++m) {
            int4v a = *(const int4v*)(actIn + (size_t)(row0 + m * 16 + col) * 1024 + kt * 64 + lg * 16);
            acc[m] = __builtin_amdgcn_mfma_i32_16x16x64_i8(a, b, acc[m], 0, 0, 0);
        }
    }
    if (col < 10) {
        const float sfc = (float)(*(const double*)(ws + OFF_SFC/4));
        const float bb  = bfc[col];
        #pragma unroll
        for (int m = 0; m < 2; ++m)
            #pragma unroll
            for (int reg = 0; reg < 4; ++reg)
                out[(size_t)(row0 + m * 16 + lg * 4 + reg) * 10 + col] = (float)acc[m][reg] * sfc + bb;
    }
}

// ---------------------------------------------------------------------------
// FALLBACK fused (LDS popcount version) — used only if ws too small.
// ---------------------------------------------------------------------------
__global__ __launch_bounds__(512) void bnn_fused_lds(
    const float* __restrict__ x,
    const uint32_t* __restrict__ ws,
    const float* __restrict__ bfc,
    float* __restrict__ out)
{
    __shared__ alignas(16) uint32_t bufA[RWS][32];
    __shared__ alignas(16) uint32_t bufB[RWS][32];
    const int t    = threadIdx.x;
    const int lane = t & 63;
    const int wv   = t >> 6;
    const int row0 = blockIdx.x * RWS;

    #pragma unroll
    for (int rr = 0; rr < 2; ++rr) {
        const int r = wv + 8 * rr;
        const float* xr = x + (size_t)(row0 + r) * 784;
        #pragma unroll
        for (int k = 0; k < 13; ++k) {
            const int idx = k * 64 + lane;
            const bool bit = (idx < 784) && (xr[idx] >= 0.5f);
            unsigned long long m = __ballot(bit);
            if (lane == 0) *(uint64_t*)(&bufA[r][2 * k]) = m;
        }
        if (lane == 0) {
            *(uint64_t*)(&bufA[r][26]) = 0ull;
            *(uint64_t*)(&bufA[r][28]) = 0ull;
            *(uint64_t*)(&bufA[r][30]) = 0ull;
        }
    }
    __syncthreads();

    const uint32_t* Wbase[3] = { ws + OFF_W1/4, ws + OFF_W2/4, ws + OFF_W3/4 };
    const int*      Tbase[3] = { (const int*)(ws + OFF_T1/4), (const int*)(ws + OFF_T2/4), (const int*)(ws + OFF_T3/4) };

    uint32_t (*cur)[32] = bufA;
    uint32_t (*nxt)[32] = bufB;
    const int c0 = t, c1 = t + 512;

    for (int l = 0; l < 3; ++l) {
        uint32_t W0[32], W1[32];
        {
            const uint4* p0 = (const uint4*)(Wbase[l] + (size_t)c0 * 32);
            const uint4* p1 = (const uint4*)(Wbase[l] + (size_t)c1 * 32);
            #pragma unroll
            for (int i = 0; i < 8; ++i) { ((uint4*)W0)[i] = p0[i]; ((uint4*)W1)[i] = p1[i]; }
        }
        const int T0 = Tbase[l][c0];
        const int T1 = Tbase[l][c1];

        for (int r = 0; r < RWS; ++r) {
            uint32_t A[32];
            #pragma unroll
            for (int i = 0; i < 8; ++i) ((uint4*)A)[i] = ((const uint4*)cur[r])[i];
            int pa = 0, pb = 0, pc = 0, pd = 0;
            #pragma unroll
            for (int i = 0; i < 16; ++i) {
                pa += __popc(A[i]      ^ W0[i]);
                pb += __popc(A[i + 16] ^ W0[i + 16]);
                pc += __popc(A[i]      ^ W1[i]);
                pd += __popc(A[i + 16] ^ W1[i + 16]);
            }
            unsigned long long m0 = __ballot((pa + pb) <= T0);
            unsigned long long m1 = __ballot((pc + pd) <= T1);
            if (lane == 0) {
                *(uint64_t*)(&nxt[r][2 * wv])      = m0;
                *(uint64_t*)(&nxt[r][16 + 2 * wv]) = m1;
            }
        }
        __syncthreads();
        uint32_t (*tmp)[32] = cur; cur = nxt; nxt = tmp;
    }

    if (t < RWS * 10) {
        const float sfc = (float)(*(const double*)(ws + OFF_SFC/4));
        const uint32_t* Wfc = ws + OFF_WFC/4;
        const int r = t / 10, ch = t % 10;
        const uint32_t* wrow = Wfc + ch * 32;
        int p = 0;
        #pragma unroll
        for (int i = 0; i < 32; ++i) p += __popc(cur[r][i] ^ wrow[i]);
        out[(size_t)(row0 + r) * 10 + ch] = (float)(1024 - 2 * p) * sfc + bfc[ch];
    }
}

extern "C" void kernel_launch(void* const* d_in, const int* in_sizes, int n_in,
                              void* d_out, int out_size, void* d_ws, size_t ws_size,
                              hipStream_t stream) {
    const float* x   = (const float*)d_in[0];
    const float* w1  = (const float*)d_in[1];
    const float* b1  = (const float*)d_in[2];
    const float* g1  = (const float*)d_in[3];
    const float* be1 = (const float*)d_in[4];
    const float* m1  = (const float*)d_in[5];
    const float* v1  = (const float*)d_in[6];
    const float* w2  = (const float*)d_in[7];
    const float* b2  = (const float*)d_in[8];
    const float* g2  = (const float*)d_in[9];
    const float* be2 = (const float*)d_in[10];
    const float* m2  = (const float*)d_in[11];
    const float* v2  = (const float*)d_in[12];
    const float* w3  = (const float*)d_in[13];
    const float* b3  = (const float*)d_in[14];
    const float* g3  = (const float*)d_in[15];
    const float* be3 = (const float*)d_in[16];
    const float* m3  = (const float*)d_in[17];
    const float* v3  = (const float*)d_in[18];
    const float* wfc = (const float*)d_in[19];
    const float* bfc = (const float*)d_in[20];
    uint32_t* ws = (uint32_t*)d_ws;
    float* out = (float*)d_out;

    const bool split = (ws_size >= (size_t)WS_NEED_V12);

    // prep: weights only (x-pack folded into layer 1)
    bnn_prep<<<385, 256, 0, stream>>>(
        w1, b1, g1, be1, m1, v1,
        w2, b2, g2, be2, m2, v2,
        w3, b3, g3, be3, m3, v3,
        wfc, ws);

    if (split) {
        uint8_t* S0 = (uint8_t*)ws + OFF_S0;
        uint8_t* S1 = (uint8_t*)ws + OFF_S1;
        const uint8_t* F1 = (const uint8_t*)ws + OFF_F1;
        const uint8_t* F2 = (const uint8_t*)ws + OFF_F2;
        const uint8_t* F3 = (const uint8_t*)ws + OFF_F3;
        bnn_layer_mfma<true ><<<512, 512, 0, stream>>>(x, nullptr, F1, (const int*)(ws + OFF_C1/4), S1);
        bnn_layer_mfma<false><<<512, 512, 0, stream>>>(x, S1,      F2, (const int*)(ws + OFF_C2/4), S0);
        bnn_layer_mfma<false><<<512, 512, 0, stream>>>(x, S0,      F3, (const int*)(ws + OFF_C3/4), S1);
        bnn_fc_mfma<<<256, 64, 0, stream>>>(S1, ws, bfc, out);
    } else {
        bnn_fused_lds<<<8192 / RWS, 512, 0, stream>>>(x, ws, bfc, out);
    }
}

// Round 15
// 186.089 us; speedup vs baseline: 1.0797x; 1.0797x over previous
//
#include <hip/hip_runtime.h>
#include <stdint.h>

// Workspace byte offsets
#define OFF_W1  0        // 1024*32 u32 packed sign bits, channel-major (fallback)
#define OFF_W2  131072
#define OFF_W3  262144
#define OFF_WFC 393216   // 10*32 u32 (fallback FC)
#define OFF_T1  395264   // 1024 int32 popcount thresholds (fallback)
#define OFF_T2  399360
#define OFF_T3  403456
#define OFF_SFC 407552   // double: mean|wfc|
// MFMA: fragment-ordered i8 weight files. Layout per layer:
//   frag[(nt*16 + kt)*1024 + lane*16 + e], nt=ch>>4 (64), kt=k>>6 (16),
//   lane = (ch&15) | (((k>>4)&3)<<4), e = k&15.  1 MB per layer.
#define OFF_F1  409600
#define OFF_F2  1458176
#define OFF_F3  2506752
#define OFF_FFC 3555328  // 16 KB: wfc frags (16 cols: 10 real + 6 don't-care)
#define OFF_C1  3571712  // 1024 int32 dot-form thresholds (act = dot >= Cdot)
#define OFF_C2  3575808
#define OFF_C3  3579904
// Two 8 MB i8 activation buffers [8192][1024], plain row-major.
#define OFF_S0  3584000
#define OFF_S1  11972608
#define WS_NEED_V12 20361216u
#define RWS 16           // rows per block in fallback fused kernel

typedef int int4v __attribute__((ext_vector_type(4)));

// ---------------------------------------------------------------------------
// Prep — 385 blocks (x-pack folded into layer-1):
//   blocks 0..383: W bitpack (fallback) + i8 frag file + thresholds (Td, Cdot)
//   block 384: wfc (both forms) + mean|wfc|.
// ---------------------------------------------------------------------------
__global__ __launch_bounds__(256) void bnn_prep(
    const float* __restrict__ w1, const float* __restrict__ b1, const float* __restrict__ g1,
    const float* __restrict__ be1, const float* __restrict__ m1, const float* __restrict__ v1,
    const float* __restrict__ w2, const float* __restrict__ b2, const float* __restrict__ g2,
    const float* __restrict__ be2, const float* __restrict__ m2, const float* __restrict__ v2,
    const float* __restrict__ w3, const float* __restrict__ b3, const float* __restrict__ g3,
    const float* __restrict__ be3, const float* __restrict__ m3, const float* __restrict__ v3,
    const float* __restrict__ wfc,
    uint32_t* __restrict__ ws)
{
    const int blk  = blockIdx.x;
    const int t    = threadIdx.x;
    const int lane = t & 63;
    const int wv   = t >> 6;

    if (blk < 384) {
        const int gid = blk * 256 + t;      // 0..98303
        const int l   = gid >> 15;          // layer 0..2 (32768 words each)
        const int rem = gid & 32767;
        const int o   = rem >> 5;           // channel
        const int k32 = rem & 31;           // word within channel
        const float *w, *bb, *g, *be, *m, *v;
        int K; uint32_t *Wp, *Fl; int *T, *Cdl;
        if (l == 0)      { w=w1; bb=b1; g=g1; be=be1; m=m1; v=v1; K=784;
                           Wp = ws + OFF_W1/4; Fl = ws + OFF_F1/4;
                           T = (int*)(ws + OFF_T1/4); Cdl = (int*)(ws + OFF_C1/4); }
        else if (l == 1) { w=w2; bb=b2; g=g2; be=be2; m=m2; v=v2; K=1024;
                           Wp = ws + OFF_W2/4; Fl = ws + OFF_F2/4;
                           T = (int*)(ws + OFF_T2/4); Cdl = (int*)(ws + OFF_C2/4); }
        else             { w=w3; bb=b3; g=g3; be=be3; m=m3; v=v3; K=1024;
                           Wp = ws + OFF_W3/4; Fl = ws + OFF_F3/4;
                           T = (int*)(ws + OFF_T3/4); Cdl = (int*)(ws + OFF_C3/4); }

        const int base = 32 * k32;
        uint32_t bits = 0;
        double s = 0.0;
        if (base < K) {
            const float4* p = (const float4*)(w + (size_t)o * K + base);
            const int n4 = (K - base >= 32) ? 8 : 4;   // K=784, k32=24 -> 16 elems
            for (int i = 0; i < n4; ++i) {
                float4 q = p[i];
                bits |= (q.x >= 0.0f) ? (1u << (4*i + 0)) : 0u;
                bits |= (q.y >= 0.0f) ? (1u << (4*i + 1)) : 0u;
                bits |= (q.z >= 0.0f) ? (1u << (4*i + 2)) : 0u;
                bits |= (q.w >= 0.0f) ? (1u << (4*i + 3)) : 0u;
                s += fabs((double)q.x) + fabs((double)q.y)
                   + fabs((double)q.z) + fabs((double)q.w);
            }
        }
        // half-wave (32-lane) xor tree: all lanes of the half get channel sum
        #pragma unroll
        for (int mask = 1; mask <= 16; mask <<= 1)
            s += __shfl_xor(s, mask, 64);
        if (k32 == 0) {
            double scale = s / (double)K;                        // mean|w| > 0
            double r = (double)g[o] / sqrt((double)v[o] + 1e-5); // > 0
            double tt = (((double)m[o] - (double)bb[o]) * r - (double)be[o]) / (scale * r);
            double C  = ceil(tt);                                // act=+1 iff dot >= C
            double Cc = fmax(fmin(C, 100000.0), -100000.0);
            Cdl[o] = (int)Cc;
            double Td = floor(((double)K - C) * 0.5);
            Td = fmax(fmin(Td, 100000.0), -1.0);
            T[o] = (int)Td;
        }
        Wp[(size_t)o * 32 + k32] = bits;                          // bitpacked

        // i8 fragment bytes: 32 bits -> two 16-byte groups in frag order.
        const int nt = o >> 4;
        #pragma unroll
        for (int g2i = 0; g2i < 2; ++g2i) {
            const int kg = base + g2i * 16;
            const int kt = kg >> 6;
            const int lane16 = (o & 15) | (((kg >> 4) & 3) << 4);
            uint32_t fb[4];
            #pragma unroll
            for (int wd = 0; wd < 4; ++wd) {
                uint32_t vv = 0;
                #pragma unroll
                for (int bj = 0; bj < 4; ++bj) {
                    const int idx = g2i*16 + wd*4 + bj;
                    const int kk  = base + idx;
                    uint32_t byte = (kk < K) ? (((bits >> idx) & 1u) ? 0x01u : 0xFFu) : 0x00u;
                    vv |= byte << (8*bj);
                }
                fb[wd] = vv;
            }
            uint32_t* dst = Fl + (size_t)((nt*16 + kt) * 256 + lane16 * 4);
            *(uint4*)dst = *(uint4*)fb;
        }
    } else {
        // wfc: 320 words (10 ch x 32); thread t does word t and (t<64) t+256
        uint32_t* Wp  = ws + OFF_WFC/4;
        uint32_t* Ffc = ws + OFF_FFC/4;
        double s = 0.0;
        #pragma unroll
        for (int part = 0; part < 2; ++part) {
            const int tt_ = t + part * 256;
            if (part == 1 && t >= 64) break;
            const int o = tt_ >> 5, k32 = tt_ & 31;
            const int base = 32 * k32;
            const float4* p = (const float4*)(wfc + o * 1024 + base);
            uint32_t bits = 0;
            #pragma unroll
            for (int i = 0; i < 8; ++i) {
                float4 q = p[i];
                bits |= (q.x >= 0.0f) ? (1u << (4*i + 0)) : 0u;
                bits |= (q.y >= 0.0f) ? (1u << (4*i + 1)) : 0u;
                bits |= (q.z >= 0.0f) ? (1u << (4*i + 2)) : 0u;
                bits |= (q.w >= 0.0f) ? (1u << (4*i + 3)) : 0u;
                s += fabs((double)q.x) + fabs((double)q.y)
                   + fabs((double)q.z) + fabs((double)q.w);
            }
            Wp[tt_] = bits;
            #pragma unroll
            for (int g2i = 0; g2i < 2; ++g2i) {
                const int kg = base + g2i * 16;
                const int kt = kg >> 6;
                const int lane16 = (o & 15) | (((kg >> 4) & 3) << 4);
                uint32_t fb[4];
                #pragma unroll
                for (int wd = 0; wd < 4; ++wd) {
                    uint32_t vv = 0;
                    #pragma unroll
                    for (int bj = 0; bj < 4; ++bj) {
                        const int idx = g2i*16 + wd*4 + bj;
                        vv |= (((bits >> idx) & 1u) ? 0x01u : 0xFFu) << (8*bj);
                    }
                    fb[wd] = vv;
                }
                *(uint4*)(Ffc + (size_t)(kt * 256 + lane16 * 4)) = *(uint4*)fb;
            }
        }
        __shared__ double red[4];
        #pragma unroll
        for (int off = 32; off > 0; off >>= 1) s += __shfl_down(s, off, 64);
        if (lane == 0) red[wv] = s;
        __syncthreads();
        if (t == 0)
            *(double*)(ws + OFF_SFC/4) = (red[0] + red[1] + red[2] + red[3]) / 10240.0;
    }
}

// ---------------------------------------------------------------------------
// v14 (R24): R13 inner loop (PLAIN loads — R14's nontemporal_load bypassed
// L2, turning 128 MB/layer of L2-resident B reads into L3/HBM traffic:
// FETCH 58 MB/dispatch, layers 54us, occupancy 16%) + the R14 template<FIRST>
// x-pack fold (layer 1 stages straight from x; no prep x-pack pass, no 16 MB
// S0 round-trip). BM=64 x BN=256, grid 512 (2 blocks/CU).
// ---------------------------------------------------------------------------
template<bool FIRST>
__global__ __launch_bounds__(512) void bnn_layer_mfma(
    const float*   __restrict__ x,       // used when FIRST
    const uint8_t* __restrict__ actIn,   // used when !FIRST
    const uint8_t* __restrict__ Wfrag,   // 1 MB fragment file
    const int*     __restrict__ Cdot,    // 1024 thresholds
    uint8_t* __restrict__ actOut)        // [8192][1024] i8
{
    __shared__ uint8_t At[64 * 1024];
    const int t    = threadIdx.x;
    const int lane = t & 63;
    const int wv   = t >> 6;            // 0..7
    const int rg   = blockIdx.x >> 2;   // 0..127
    const int cg   = blockIdx.x & 3;    // 0..3
    const int row0 = rg * 64;

    if (FIRST) {
        // stage from x: 64 rows x 256 u32 words; word w<196 packs 4 floats,
        // else zero pad (784 = 4*196 exactly). Consecutive t -> consecutive
        // w -> coalesced float4 reads.
        #pragma unroll
        for (int i = 0; i < 32; ++i) {
            const int id  = t + i * 512;     // 0..16383
            const int row = id >> 8;         // 0..63
            const int w   = id & 255;        // u32 word in row
            uint32_t wval = 0;
            if (w < 196) {
                const float4 q = *(const float4*)(x + (size_t)(row0 + row) * 784 + 4 * w);
                wval  = ((q.x >= 0.5f) ? 0x01u : 0xFFu);
                wval |= ((q.y >= 0.5f) ? 0x01u : 0xFFu) << 8;
                wval |= ((q.z >= 0.5f) ? 0x01u : 0xFFu) << 16;
                wval |= ((q.w >= 0.5f) ? 0x01u : 0xFFu) << 24;
            }
            *(uint32_t*)(At + row * 1024 + ((4 * w) ^ ((row & 7) << 4))) = wval;
        }
    } else {
        // stage A tile (64 KB): 4096 16-B chunks, thread does 8, coalesced.
        #pragma unroll
        for (int i = 0; i < 8; ++i) {
            const int id  = t + i * 512;     // 0..4095
            const int row = id >> 6;
            const int ks  = id & 63;
            uint4 v = *(const uint4*)(actIn + (size_t)(row0 + row) * 1024 + ks * 16);
            *(uint4*)(At + row * 1024 + ((ks * 16) ^ ((row & 7) << 4))) = v;
        }
    }
    __syncthreads();

    const int col = lane & 15;
    const int lg  = lane >> 4;          // 0..3
    const int nq  = cg * 16 + wv * 2;   // first of this wave's 2 n-tiles (0..63)

    int4v acc[4][2];
    #pragma unroll
    for (int m = 0; m < 4; ++m)
        #pragma unroll
        for (int j = 0; j < 2; ++j)
            acc[m][j] = (int4v){0, 0, 0, 0};

    // B double buffer, 1 kt deep (kt parity static after full unroll).
    int4v bq[2][2];
    #pragma unroll
    for (int j = 0; j < 2; ++j)
        bq[0][j] = *(const int4v*)(Wfrag + ((size_t)((nq + j) * 16) << 10) + lane * 16);

    #pragma unroll
    for (int kt = 0; kt < 16; ++kt) {
        const int cb = kt & 1, nb = cb ^ 1;
        if (kt < 15) {
            #pragma unroll
            for (int j = 0; j < 2; ++j)
                bq[nb][j] = *(const int4v*)(Wfrag + ((size_t)((nq + j) * 16 + kt + 1) << 10) + lane * 16);
        }
        const int k0 = kt * 64 + lg * 16;
        int4v a[4];
        #pragma unroll
        for (int m = 0; m < 4; ++m)
            a[m] = *(const int4v*)(At + (m * 16 + col) * 1024 + (k0 ^ ((col & 7) << 4)));
        #pragma unroll
        for (int m = 0; m < 4; ++m)
            #pragma unroll
            for (int j = 0; j < 2; ++j)
                acc[m][j] = __builtin_amdgcn_mfma_i32_16x16x64_i8(a[m], bq[cb][j], acc[m][j], 0, 0, 0);
    }

    // ---- epilogue: threshold -> i8 act bytes, plain row-major global store.
    #pragma unroll
    for (int j = 0; j < 2; ++j) {
        const int ch  = (nq + j) * 16 + col;
        const int thr = Cdot[ch];
        #pragma unroll
        for (int m = 0; m < 4; ++m) {
            #pragma unroll
            for (int reg = 0; reg < 4; ++reg) {
                const int row = row0 + m * 16 + lg * 4 + reg;
                actOut[(size_t)row * 1024 + ch] =
                    (acc[m][j][reg] >= thr) ? (uint8_t)0x01 : (uint8_t)0xFF;
            }
        }
    }
}

// ---------------------------------------------------------------------------
// FC: one wave per 32 rows; A fragments loaded straight from global (L2-hot).
// ---------------------------------------------------------------------------
__global__ __launch_bounds__(64) void bnn_fc_mfma(
    const uint8_t* __restrict__ actIn,
    const uint32_t* __restrict__ ws,
    const float* __restrict__ bfc,
    float* __restrict__ out)
{
    const int lane = threadIdx.x;
    const int col  = lane & 15;
    const int lg   = lane >> 4;
    const int row0 = blockIdx.x * 32;
    const uint8_t* Bf = (const uint8_t*)ws + OFF_FFC;

    int4v acc[2];
    acc[0] = (int4v){0, 0, 0, 0};
    acc[1] = (int4v){0, 0, 0, 0};

    #pragma unroll
    for (int kt = 0; kt < 16; ++kt) {
        int4v b = *(const int4v*)(Bf + ((size_t)kt << 10) + lane * 16);
        #pragma unroll
        for (int m = 0; m < 2; ++m) {
            int4v a = *(const int4v*)(actIn + (size_t)(row0 + m * 16 + col) * 1024 + kt * 64 + lg * 16);
            acc[m] = __builtin_amdgcn_mfma_i32_16x16x64_i8(a, b, acc[m], 0, 0, 0);
        }
    }
    if (col < 10) {
        const float sfc = (float)(*(const double*)(ws + OFF_SFC/4));
        const float bb  = bfc[col];
        #pragma unroll
        for (int m = 0; m < 2; ++m)
            #pragma unroll
            for (int reg = 0; reg < 4; ++reg)
                out[(size_t)(row0 + m * 16 + lg * 4 + reg) * 10 + col] = (float)acc[m][reg] * sfc + bb;
    }
}

// ---------------------------------------------------------------------------
// FALLBACK fused (LDS popcount version) — used only if ws too small.
// ---------------------------------------------------------------------------
__global__ __launch_bounds__(512) void bnn_fused_lds(
    const float* __restrict__ x,
    const uint32_t* __restrict__ ws,
    const float* __restrict__ bfc,
    float* __restrict__ out)
{
    __shared__ alignas(16) uint32_t bufA[RWS][32];
    __shared__ alignas(16) uint32_t bufB[RWS][32];
    const int t    = threadIdx.x;
    const int lane = t & 63;
    const int wv   = t >> 6;
    const int row0 = blockIdx.x * RWS;

    #pragma unroll
    for (int rr = 0; rr < 2; ++rr) {
        const int r = wv + 8 * rr;
        const float* xr = x + (size_t)(row0 + r) * 784;
        #pragma unroll
        for (int k = 0; k < 13; ++k) {
            const int idx = k * 64 + lane;
            const bool bit = (idx < 784) && (xr[idx] >= 0.5f);
            unsigned long long m = __ballot(bit);
            if (lane == 0) *(uint64_t*)(&bufA[r][2 * k]) = m;
        }
        if (lane == 0) {
            *(uint64_t*)(&bufA[r][26]) = 0ull;
            *(uint64_t*)(&bufA[r][28]) = 0ull;
            *(uint64_t*)(&bufA[r][30]) = 0ull;
        }
    }
    __syncthreads();

    const uint32_t* Wbase[3] = { ws + OFF_W1/4, ws + OFF_W2/4, ws + OFF_W3/4 };
    const int*      Tbase[3] = { (const int*)(ws + OFF_T1/4), (const int*)(ws + OFF_T2/4), (const int*)(ws + OFF_T3/4) };

    uint32_t (*cur)[32] = bufA;
    uint32_t (*nxt)[32] = bufB;
    const int c0 = t, c1 = t + 512;

    for (int l = 0; l < 3; ++l) {
        uint32_t W0[32], W1[32];
        {
            const uint4* p0 = (const uint4*)(Wbase[l] + (size_t)c0 * 32);
            const uint4* p1 = (const uint4*)(Wbase[l] + (size_t)c1 * 32);
            #pragma unroll
            for (int i = 0; i < 8; ++i) { ((uint4*)W0)[i] = p0[i]; ((uint4*)W1)[i] = p1[i]; }
        }
        const int T0 = Tbase[l][c0];
        const int T1 = Tbase[l][c1];

        for (int r = 0; r < RWS; ++r) {
            uint32_t A[32];
            #pragma unroll
            for (int i = 0; i < 8; ++i) ((uint4*)A)[i] = ((const uint4*)cur[r])[i];
            int pa = 0, pb = 0, pc = 0, pd = 0;
            #pragma unroll
            for (int i = 0; i < 16; ++i) {
                pa += __popc(A[i]      ^ W0[i]);
                pb += __popc(A[i + 16] ^ W0[i + 16]);
                pc += __popc(A[i]      ^ W1[i]);
                pd += __popc(A[i + 16] ^ W1[i + 16]);
            }
            unsigned long long m0 = __ballot((pa + pb) <= T0);
            unsigned long long m1 = __ballot((pc + pd) <= T1);
            if (lane == 0) {
                *(uint64_t*)(&nxt[r][2 * wv])      = m0;
                *(uint64_t*)(&nxt[r][16 + 2 * wv]) = m1;
            }
        }
        __syncthreads();
        uint32_t (*tmp)[32] = cur; cur = nxt; nxt = tmp;
    }

    if (t < RWS * 10) {
        const float sfc = (float)(*(const double*)(ws + OFF_SFC/4));
        const uint32_t* Wfc = ws + OFF_WFC/4;
        const int r = t / 10, ch = t % 10;
        const uint32_t* wrow = Wfc + ch * 32;
        int p = 0;
        #pragma unroll
        for (int i = 0; i < 32; ++i) p += __popc(cur[r][i] ^ wrow[i]);
        out[(size_t)(row0 + r) * 10 + ch] = (float)(1024 - 2 * p) * sfc + bfc[ch];
    }
}

extern "C" void kernel_launch(void* const* d_in, const int* in_sizes, int n_in,
                              void* d_out, int out_size, void* d_ws, size_t ws_size,
                              hipStream_t stream) {
    const float* x   = (const float*)d_in[0];
    const float* w1  = (const float*)d_in[1];
    const float* b1  = (const float*)d_in[2];
    const float* g1  = (const float*)d_in[3];
    const float* be1 = (const float*)d_in[4];
    const float* m1  = (const float*)d_in[5];
    const float* v1  = (const float*)d_in[6];
    const float* w2  = (const float*)d_in[7];
    const float* b2  = (const float*)d_in[8];
    const float* g2  = (const float*)d_in[9];
    const float* be2 = (const float*)d_in[10];
    const float* m2  = (const float*)d_in[11];
    const float* v2  = (const float*)d_in[12];
    const float* w3  = (const float*)d_in[13];
    const float* b3  = (const float*)d_in[14];
    const float* g3  = (const float*)d_in[15];
    const float* be3 = (const float*)d_in[16];
    const float* m3  = (const float*)d_in[17];
    const float* v3  = (const float*)d_in[18];
    const float* wfc = (const float*)d_in[19];
    const float* bfc = (const float*)d_in[20];
    uint32_t* ws = (uint32_t*)d_ws;
    float* out = (float*)d_out;

    const bool split = (ws_size >= (size_t)WS_NEED_V12);

    // prep: weights only (x-pack folded into layer 1)
    bnn_prep<<<385, 256, 0, stream>>>(
        w1, b1, g1, be1, m1, v1,
        w2, b2, g2, be2, m2, v2,
        w3, b3, g3, be3, m3, v3,
        wfc, ws);

    if (split) {
        uint8_t* S0 = (uint8_t*)ws + OFF_S0;
        uint8_t* S1 = (uint8_t*)ws + OFF_S1;
        const uint8_t* F1 = (const uint8_t*)ws + OFF_F1;
        const uint8_t* F2 = (const uint8_t*)ws + OFF_F2;
        const uint8_t* F3 = (const uint8_t*)ws + OFF_F3;
        bnn_layer_mfma<true ><<<512, 512, 0, stream>>>(x, nullptr, F1, (const int*)(ws + OFF_C1/4), S1);
        bnn_layer_mfma<false><<<512, 512, 0, stream>>>(x, S1,      F2, (const int*)(ws + OFF_C2/4), S0);
        bnn_layer_mfma<false><<<512, 512, 0, stream>>>(x, S0,      F3, (const int*)(ws + OFF_C3/4), S1);
        bnn_fc_mfma<<<256, 64, 0, stream>>>(S1, ws, bfc, out);
    } else {
        bnn_fused_lds<<<8192 / RWS, 512, 0, stream>>>(x, ws, bfc, out);
    }
}

// Round 16
// 164.708 us; speedup vs baseline: 1.2199x; 1.1298x over previous
//
#include <hip/hip_runtime.h>
#include <stdint.h>

// Workspace byte offsets
#define OFF_W1  0        // 1024*32 u32 packed sign bits, channel-major (fallback)
#define OFF_W2  131072
#define OFF_W3  262144
#define OFF_WFC 393216   // 10*32 u32 (fallback FC)
#define OFF_T1  395264   // 1024 int32 popcount thresholds (fallback)
#define OFF_T2  399360
#define OFF_T3  403456
#define OFF_SFC 407552   // double: mean|wfc|
// MFMA: fragment-ordered i8 weight files. Layout per layer:
//   frag[(nt*16 + kt)*1024 + lane*16 + e], nt=ch>>4 (64), kt=k>>6 (16),
//   lane = (ch&15) | (((k>>4)&3)<<4), e = k&15.  1 MB per layer.
#define OFF_F1  409600
#define OFF_F2  1458176
#define OFF_F3  2506752
#define OFF_FFC 3555328  // 16 KB: wfc frags (16 cols: 10 real + 6 don't-care)
#define OFF_C1  3571712  // 1024 int32 dot-form thresholds (act = dot >= Cdot)
#define OFF_C2  3575808
#define OFF_C3  3579904
// Two 8 MB i8 activation buffers [8192][1024], plain row-major.
#define OFF_S0  3584000
#define OFF_S1  11972608
#define WS_NEED_V12 20361216u
#define RWS 16           // rows per block in fallback fused kernel

typedef int int4v __attribute__((ext_vector_type(4)));

// ---------------------------------------------------------------------------
// Prep — 385 blocks (x-pack folded into layer-1):
//   blocks 0..383: W bitpack (fallback) + i8 frag file + thresholds (Td, Cdot)
//   block 384: wfc (both forms) + mean|wfc|.
// ---------------------------------------------------------------------------
__global__ __launch_bounds__(256) void bnn_prep(
    const float* __restrict__ w1, const float* __restrict__ b1, const float* __restrict__ g1,
    const float* __restrict__ be1, const float* __restrict__ m1, const float* __restrict__ v1,
    const float* __restrict__ w2, const float* __restrict__ b2, const float* __restrict__ g2,
    const float* __restrict__ be2, const float* __restrict__ m2, const float* __restrict__ v2,
    const float* __restrict__ w3, const float* __restrict__ b3, const float* __restrict__ g3,
    const float* __restrict__ be3, const float* __restrict__ m3, const float* __restrict__ v3,
    const float* __restrict__ wfc,
    uint32_t* __restrict__ ws)
{
    const int blk  = blockIdx.x;
    const int t    = threadIdx.x;
    const int lane = t & 63;
    const int wv   = t >> 6;

    if (blk < 384) {
        const int gid = blk * 256 + t;      // 0..98303
        const int l   = gid >> 15;          // layer 0..2 (32768 words each)
        const int rem = gid & 32767;
        const int o   = rem >> 5;           // channel
        const int k32 = rem & 31;           // word within channel
        const float *w, *bb, *g, *be, *m, *v;
        int K; uint32_t *Wp, *Fl; int *T, *Cdl;
        if (l == 0)      { w=w1; bb=b1; g=g1; be=be1; m=m1; v=v1; K=784;
                           Wp = ws + OFF_W1/4; Fl = ws + OFF_F1/4;
                           T = (int*)(ws + OFF_T1/4); Cdl = (int*)(ws + OFF_C1/4); }
        else if (l == 1) { w=w2; bb=b2; g=g2; be=be2; m=m2; v=v2; K=1024;
                           Wp = ws + OFF_W2/4; Fl = ws + OFF_F2/4;
                           T = (int*)(ws + OFF_T2/4); Cdl = (int*)(ws + OFF_C2/4); }
        else             { w=w3; bb=b3; g=g3; be=be3; m=m3; v=v3; K=1024;
                           Wp = ws + OFF_W3/4; Fl = ws + OFF_F3/4;
                           T = (int*)(ws + OFF_T3/4); Cdl = (int*)(ws + OFF_C3/4); }

        const int base = 32 * k32;
        uint32_t bits = 0;
        double s = 0.0;
        if (base < K) {
            const float4* p = (const float4*)(w + (size_t)o * K + base);
            const int n4 = (K - base >= 32) ? 8 : 4;   // K=784, k32=24 -> 16 elems
            for (int i = 0; i < n4; ++i) {
                float4 q = p[i];
                bits |= (q.x >= 0.0f) ? (1u << (4*i + 0)) : 0u;
                bits |= (q.y >= 0.0f) ? (1u << (4*i + 1)) : 0u;
                bits |= (q.z >= 0.0f) ? (1u << (4*i + 2)) : 0u;
                bits |= (q.w >= 0.0f) ? (1u << (4*i + 3)) : 0u;
                s += fabs((double)q.x) + fabs((double)q.y)
                   + fabs((double)q.z) + fabs((double)q.w);
            }
        }
        // half-wave (32-lane) xor tree: all lanes of the half get channel sum
        #pragma unroll
        for (int mask = 1; mask <= 16; mask <<= 1)
            s += __shfl_xor(s, mask, 64);
        if (k32 == 0) {
            double scale = s / (double)K;                        // mean|w| > 0
            double r = (double)g[o] / sqrt((double)v[o] + 1e-5); // > 0
            double tt = (((double)m[o] - (double)bb[o]) * r - (double)be[o]) / (scale * r);
            double C  = ceil(tt);                                // act=+1 iff dot >= C
            double Cc = fmax(fmin(C, 100000.0), -100000.0);
            Cdl[o] = (int)Cc;
            double Td = floor(((double)K - C) * 0.5);
            Td = fmax(fmin(Td, 100000.0), -1.0);
            T[o] = (int)Td;
        }
        Wp[(size_t)o * 32 + k32] = bits;                          // bitpacked

        // i8 fragment bytes: 32 bits -> two 16-byte groups in frag order.
        const int nt = o >> 4;
        #pragma unroll
        for (int g2i = 0; g2i < 2; ++g2i) {
            const int kg = base + g2i * 16;
            const int kt = kg >> 6;
            const int lane16 = (o & 15) | (((kg >> 4) & 3) << 4);
            uint32_t fb[4];
            #pragma unroll
            for (int wd = 0; wd < 4; ++wd) {
                uint32_t vv = 0;
                #pragma unroll
                for (int bj = 0; bj < 4; ++bj) {
                    const int idx = g2i*16 + wd*4 + bj;
                    const int kk  = base + idx;
                    uint32_t byte = (kk < K) ? (((bits >> idx) & 1u) ? 0x01u : 0xFFu) : 0x00u;
                    vv |= byte << (8*bj);
                }
                fb[wd] = vv;
            }
            uint32_t* dst = Fl + (size_t)((nt*16 + kt) * 256 + lane16 * 4);
            *(uint4*)dst = *(uint4*)fb;
        }
    } else {
        // wfc: 320 words (10 ch x 32); thread t does word t and (t<64) t+256
        uint32_t* Wp  = ws + OFF_WFC/4;
        uint32_t* Ffc = ws + OFF_FFC/4;
        double s = 0.0;
        #pragma unroll
        for (int part = 0; part < 2; ++part) {
            const int tt_ = t + part * 256;
            if (part == 1 && t >= 64) break;
            const int o = tt_ >> 5, k32 = tt_ & 31;
            const int base = 32 * k32;
            const float4* p = (const float4*)(wfc + o * 1024 + base);
            uint32_t bits = 0;
            #pragma unroll
            for (int i = 0; i < 8; ++i) {
                float4 q = p[i];
                bits |= (q.x >= 0.0f) ? (1u << (4*i + 0)) : 0u;
                bits |= (q.y >= 0.0f) ? (1u << (4*i + 1)) : 0u;
                bits |= (q.z >= 0.0f) ? (1u << (4*i + 2)) : 0u;
                bits |= (q.w >= 0.0f) ? (1u << (4*i + 3)) : 0u;
                s += fabs((double)q.x) + fabs((double)q.y)
                   + fabs((double)q.z) + fabs((double)q.w);
            }
            Wp[tt_] = bits;
            #pragma unroll
            for (int g2i = 0; g2i < 2; ++g2i) {
                const int kg = base + g2i * 16;
                const int kt = kg >> 6;
                const int lane16 = (o & 15) | (((kg >> 4) & 3) << 4);
                uint32_t fb[4];
                #pragma unroll
                for (int wd = 0; wd < 4; ++wd) {
                    uint32_t vv = 0;
                    #pragma unroll
                    for (int bj = 0; bj < 4; ++bj) {
                        const int idx = g2i*16 + wd*4 + bj;
                        vv |= (((bits >> idx) & 1u) ? 0x01u : 0xFFu) << (8*bj);
                    }
                    fb[wd] = vv;
                }
                *(uint4*)(Ffc + (size_t)(kt * 256 + lane16 * 4)) = *(uint4*)fb;
            }
        }
        __shared__ double red[4];
        #pragma unroll
        for (int off = 32; off > 0; off >>= 1) s += __shfl_down(s, off, 64);
        if (lane == 0) red[wv] = s;
        __syncthreads();
        if (t == 0)
            *(double*)(ws + OFF_SFC/4) = (red[0] + red[1] + red[2] + red[3]) / 10240.0;
    }
}

// ---------------------------------------------------------------------------
// v15 (R25): XCD-aware block swizzle for producer-consumer L2 locality.
// R15 counters: layers 45-49us, FETCH 52 MB/dispatch, eff. BW 1.3 TB/s.
// Cause: with rg=bid>>2, cg=bid&3 and hw round-robin xcd=bid%8, the 4 blocks
// sharing a row-tile land on 4 DIFFERENT XCDs -> every A-tile fetched into 4
// L2s (acts 32 MB, x ~100 MB demand), and layer N's output never stays in the
// reader's L2. Fix: xcd=bid&7, idx=bid>>3; rg=xcd*16+(idx>>2); cg=idx&3 —
// XCD x owns row-band [x*1024,(x+1)*1024) with ALL 4 cg quadrants, in every
// layer. Acts row-band = 1 MB/XCD, fits 4 MB L2 -> inter-layer act traffic
// stays L2-local; B per XCD = 1 MB file. Inner loops byte-identical to R13.
// ---------------------------------------------------------------------------
template<bool FIRST>
__global__ __launch_bounds__(512) void bnn_layer_mfma(
    const float*   __restrict__ x,       // used when FIRST
    const uint8_t* __restrict__ actIn,   // used when !FIRST
    const uint8_t* __restrict__ Wfrag,   // 1 MB fragment file
    const int*     __restrict__ Cdot,    // 1024 thresholds
    uint8_t* __restrict__ actOut)        // [8192][1024] i8
{
    __shared__ uint8_t At[64 * 1024];
    const int t    = threadIdx.x;
    const int lane = t & 63;
    const int wv   = t >> 6;            // 0..7
    // XCD-local decomposition: xcd owns rows [xcd*1024, (xcd+1)*1024).
    const int xcd  = blockIdx.x & 7;
    const int idx  = blockIdx.x >> 3;   // 0..63
    const int rg   = xcd * 16 + (idx >> 2);   // 0..127
    const int cg   = idx & 3;                 // 0..3
    const int row0 = rg * 64;

    if (FIRST) {
        // stage from x: 64 rows x 256 u32 words; word w<196 packs 4 floats,
        // else zero pad (784 = 4*196 exactly).
        #pragma unroll
        for (int i = 0; i < 32; ++i) {
            const int id  = t + i * 512;     // 0..16383
            const int row = id >> 8;         // 0..63
            const int w   = id & 255;        // u32 word in row
            uint32_t wval = 0;
            if (w < 196) {
                const float4 q = *(const float4*)(x + (size_t)(row0 + row) * 784 + 4 * w);
                wval  = ((q.x >= 0.5f) ? 0x01u : 0xFFu);
                wval |= ((q.y >= 0.5f) ? 0x01u : 0xFFu) << 8;
                wval |= ((q.z >= 0.5f) ? 0x01u : 0xFFu) << 16;
                wval |= ((q.w >= 0.5f) ? 0x01u : 0xFFu) << 24;
            }
            *(uint32_t*)(At + row * 1024 + ((4 * w) ^ ((row & 7) << 4))) = wval;
        }
    } else {
        // stage A tile (64 KB): 4096 16-B chunks, thread does 8, coalesced.
        #pragma unroll
        for (int i = 0; i < 8; ++i) {
            const int id  = t + i * 512;     // 0..4095
            const int row = id >> 6;
            const int ks  = id & 63;
            uint4 v = *(const uint4*)(actIn + (size_t)(row0 + row) * 1024 + ks * 16);
            *(uint4*)(At + row * 1024 + ((ks * 16) ^ ((row & 7) << 4))) = v;
        }
    }
    __syncthreads();

    const int col = lane & 15;
    const int lg  = lane >> 4;          // 0..3
    const int nq  = cg * 16 + wv * 2;   // first of this wave's 2 n-tiles (0..63)

    int4v acc[4][2];
    #pragma unroll
    for (int m = 0; m < 4; ++m)
        #pragma unroll
        for (int j = 0; j < 2; ++j)
            acc[m][j] = (int4v){0, 0, 0, 0};

    // B double buffer, 1 kt deep (kt parity static after full unroll).
    int4v bq[2][2];
    #pragma unroll
    for (int j = 0; j < 2; ++j)
        bq[0][j] = *(const int4v*)(Wfrag + ((size_t)((nq + j) * 16) << 10) + lane * 16);

    #pragma unroll
    for (int kt = 0; kt < 16; ++kt) {
        const int cb = kt & 1, nb = cb ^ 1;
        if (kt < 15) {
            #pragma unroll
            for (int j = 0; j < 2; ++j)
                bq[nb][j] = *(const int4v*)(Wfrag + ((size_t)((nq + j) * 16 + kt + 1) << 10) + lane * 16);
        }
        const int k0 = kt * 64 + lg * 16;
        int4v a[4];
        #pragma unroll
        for (int m = 0; m < 4; ++m)
            a[m] = *(const int4v*)(At + (m * 16 + col) * 1024 + (k0 ^ ((col & 7) << 4)));
        #pragma unroll
        for (int m = 0; m < 4; ++m)
            #pragma unroll
            for (int j = 0; j < 2; ++j)
                acc[m][j] = __builtin_amdgcn_mfma_i32_16x16x64_i8(a[m], bq[cb][j], acc[m][j], 0, 0, 0);
    }

    // ---- epilogue: threshold -> i8 act bytes, plain row-major global store.
    #pragma unroll
    for (int j = 0; j < 2; ++j) {
        const int ch  = (nq + j) * 16 + col;
        const int thr = Cdot[ch];
        #pragma unroll
        for (int m = 0; m < 4; ++m) {
            #pragma unroll
            for (int reg = 0; reg < 4; ++reg) {
                const int row = row0 + m * 16 + lg * 4 + reg;
                actOut[(size_t)row * 1024 + ch] =
                    (acc[m][j][reg] >= thr) ? (uint8_t)0x01 : (uint8_t)0xFF;
            }
        }
    }
}

// ---------------------------------------------------------------------------
// FC: one wave per 32 rows; same XCD-local row-band mapping (xcd owns
// rows [xcd*1024, (xcd+1)*1024) -> final acts read from local L2).
// ---------------------------------------------------------------------------
__global__ __launch_bounds__(64) void bnn_fc_mfma(
    const uint8_t* __restrict__ actIn,
    const uint32_t* __restrict__ ws,
    const float* __restrict__ bfc,
    float* __restrict__ out)
{
    const int lane = threadIdx.x;
    const int col  = lane & 15;
    const int lg   = lane >> 4;
    const int row0 = (blockIdx.x & 7) * 1024 + (blockIdx.x >> 3) * 32;
    const uint8_t* Bf = (const uint8_t*)ws + OFF_FFC;

    int4v acc[2];
    acc[0] = (int4v){0, 0, 0, 0};
    acc[1] = (int4v){0, 0, 0, 0};

    #pragma unroll
    for (int kt = 0; kt < 16; ++kt) {
        int4v b = *(const int4v*)(Bf + ((size_t)kt << 10) + lane * 16);
        #pragma unroll
        for (int m = 0; m < 2; ++m) {
            int4v a = *(const int4v*)(actIn + (size_t)(row0 + m * 16 + col) * 1024 + kt * 64 + lg * 16);
            acc[m] = __builtin_amdgcn_mfma_i32_16x16x64_i8(a, b, acc[m], 0, 0, 0);
        }
    }
    if (col < 10) {
        const float sfc = (float)(*(const double*)(ws + OFF_SFC/4));
        const float bb  = bfc[col];
        #pragma unroll
        for (int m = 0; m < 2; ++m)
            #pragma unroll
            for (int reg = 0; reg < 4; ++reg)
                out[(size_t)(row0 + m * 16 + lg * 4 + reg) * 10 + col] = (float)acc[m][reg] * sfc + bb;
    }
}

// ---------------------------------------------------------------------------
// FALLBACK fused (LDS popcount version) — used only if ws too small.
// ---------------------------------------------------------------------------
__global__ __launch_bounds__(512) void bnn_fused_lds(
    const float* __restrict__ x,
    const uint32_t* __restrict__ ws,
    const float* __restrict__ bfc,
    float* __restrict__ out)
{
    __shared__ alignas(16) uint32_t bufA[RWS][32];
    __shared__ alignas(16) uint32_t bufB[RWS][32];
    const int t    = threadIdx.x;
    const int lane = t & 63;
    const int wv   = t >> 6;
    const int row0 = blockIdx.x * RWS;

    #pragma unroll
    for (int rr = 0; rr < 2; ++rr) {
        const int r = wv + 8 * rr;
        const float* xr = x + (size_t)(row0 + r) * 784;
        #pragma unroll
        for (int k = 0; k < 13; ++k) {
            const int idx = k * 64 + lane;
            const bool bit = (idx < 784) && (xr[idx] >= 0.5f);
            unsigned long long m = __ballot(bit);
            if (lane == 0) *(uint64_t*)(&bufA[r][2 * k]) = m;
        }
        if (lane == 0) {
            *(uint64_t*)(&bufA[r][26]) = 0ull;
            *(uint64_t*)(&bufA[r][28]) = 0ull;
            *(uint64_t*)(&bufA[r][30]) = 0ull;
        }
    }
    __syncthreads();

    const uint32_t* Wbase[3] = { ws + OFF_W1/4, ws + OFF_W2/4, ws + OFF_W3/4 };
    const int*      Tbase[3] = { (const int*)(ws + OFF_T1/4), (const int*)(ws + OFF_T2/4), (const int*)(ws + OFF_T3/4) };

    uint32_t (*cur)[32] = bufA;
    uint32_t (*nxt)[32] = bufB;
    const int c0 = t, c1 = t + 512;

    for (int l = 0; l < 3; ++l) {
        uint32_t W0[32], W1[32];
        {
            const uint4* p0 = (const uint4*)(Wbase[l] + (size_t)c0 * 32);
            const uint4* p1 = (const uint4*)(Wbase[l] + (size_t)c1 * 32);
            #pragma unroll
            for (int i = 0; i < 8; ++i) { ((uint4*)W0)[i] = p0[i]; ((uint4*)W1)[i] = p1[i]; }
        }
        const int T0 = Tbase[l][c0];
        const int T1 = Tbase[l][c1];

        for (int r = 0; r < RWS; ++r) {
            uint32_t A[32];
            #pragma unroll
            for (int i = 0; i < 8; ++i) ((uint4*)A)[i] = ((const uint4*)cur[r])[i];
            int pa = 0, pb = 0, pc = 0, pd = 0;
            #pragma unroll
            for (int i = 0; i < 16; ++i) {
                pa += __popc(A[i]      ^ W0[i]);
                pb += __popc(A[i + 16] ^ W0[i + 16]);
                pc += __popc(A[i]      ^ W1[i]);
                pd += __popc(A[i + 16] ^ W1[i + 16]);
            }
            unsigned long long m0 = __ballot((pa + pb) <= T0);
            unsigned long long m1 = __ballot((pc + pd) <= T1);
            if (lane == 0) {
                *(uint64_t*)(&nxt[r][2 * wv])      = m0;
                *(uint64_t*)(&nxt[r][16 + 2 * wv]) = m1;
            }
        }
        __syncthreads();
        uint32_t (*tmp)[32] = cur; cur = nxt; nxt = tmp;
    }

    if (t < RWS * 10) {
        const float sfc = (float)(*(const double*)(ws + OFF_SFC/4));
        const uint32_t* Wfc = ws + OFF_WFC/4;
        const int r = t / 10, ch = t % 10;
        const uint32_t* wrow = Wfc + ch * 32;
        int p = 0;
        #pragma unroll
        for (int i = 0; i < 32; ++i) p += __popc(cur[r][i] ^ wrow[i]);
        out[(size_t)(row0 + r) * 10 + ch] = (float)(1024 - 2 * p) * sfc + bfc[ch];
    }
}

extern "C" void kernel_launch(void* const* d_in, const int* in_sizes, int n_in,
                              void* d_out, int out_size, void* d_ws, size_t ws_size,
                              hipStream_t stream) {
    const float* x   = (const float*)d_in[0];
    const float* w1  = (const float*)d_in[1];
    const float* b1  = (const float*)d_in[2];
    const float* g1  = (const float*)d_in[3];
    const float* be1 = (const float*)d_in[4];
    const float* m1  = (const float*)d_in[5];
    const float* v1  = (const float*)d_in[6];
    const float* w2  = (const float*)d_in[7];
    const float* b2  = (const float*)d_in[8];
    const float* g2  = (const float*)d_in[9];
    const float* be2 = (const float*)d_in[10];
    const float* m2  = (const float*)d_in[11];
    const float* v2  = (const float*)d_in[12];
    const float* w3  = (const float*)d_in[13];
    const float* b3  = (const float*)d_in[14];
    const float* g3  = (const float*)d_in[15];
    const float* be3 = (const float*)d_in[16];
    const float* m3  = (const float*)d_in[17];
    const float* v3  = (const float*)d_in[18];
    const float* wfc = (const float*)d_in[19];
    const float* bfc = (const float*)d_in[20];
    uint32_t* ws = (uint32_t*)d_ws;
    float* out = (float*)d_out;

    const bool split = (ws_size >= (size_t)WS_NEED_V12);

    // prep: weights only (x-pack folded into layer 1)
    bnn_prep<<<385, 256, 0, stream>>>(
        w1, b1, g1, be1, m1, v1,
        w2, b2, g2, be2, m2, v2,
        w3, b3, g3, be3, m3, v3,
        wfc, ws);

    if (split) {
        uint8_t* S0 = (uint8_t*)ws + OFF_S0;
        uint8_t* S1 = (uint8_t*)ws + OFF_S1;
        const uint8_t* F1 = (const uint8_t*)ws + OFF_F1;
        const uint8_t* F2 = (const uint8_t*)ws + OFF_F2;
        const uint8_t* F3 = (const uint8_t*)ws + OFF_F3;
        bnn_layer_mfma<true ><<<512, 512, 0, stream>>>(x, nullptr, F1, (const int*)(ws + OFF_C1/4), S1);
        bnn_layer_mfma<false><<<512, 512, 0, stream>>>(x, S1,      F2, (const int*)(ws + OFF_C2/4), S0);
        bnn_layer_mfma<false><<<512, 512, 0, stream>>>(x, S0,      F3, (const int*)(ws + OFF_C3/4), S1);
        bnn_fc_mfma<<<256, 64, 0, stream>>>(S1, ws, bfc, out);
    } else {
        bnn_fused_lds<<<8192 / RWS, 512, 0, stream>>>(x, ws, bfc, out);
    }
}

// Round 18
// 162.761 us; speedup vs baseline: 1.2345x; 1.0120x over previous
//
#include <hip/hip_runtime.h>
#include <stdint.h>

// Workspace byte offsets
#define OFF_W1  0        // 1024*32 u32 packed sign bits, channel-major (fallback)
#define OFF_W2  131072
#define OFF_W3  262144
#define OFF_WFC 393216   // 10*32 u32 (fallback FC)
#define OFF_T1  395264   // 1024 int32 popcount thresholds (fallback)
#define OFF_T2  399360
#define OFF_T3  403456
#define OFF_SFC 407552   // double: mean|wfc|
// MFMA: fragment-ordered i8 weight files (1 MB/layer), layout per layer:
//   frag[(nt*16 + kt)*1024 + lane*16 + e], nt=ch>>4, kt=k>>6,
//   lane = (ch&15) | (((k>>4)&3)<<4), e = k&15.
#define OFF_F1  409600
#define OFF_F2  1458176
#define OFF_F3  2506752
#define OFF_FFC 3555328  // 16 KB: wfc frags (16 cols: 10 real + 6 don't-care)
#define OFF_C1  3571712  // 1024 int32 dot-form thresholds (act = dot >= Cdot)
#define OFF_C2  3575808
#define OFF_C3  3579904
// Two 8 MB i8 activation buffers [8192][1024], plain row-major.
#define OFF_S0  3584000
#define OFF_S1  11972608
#define WS_NEED_V12 20361216u
#define RWS 16           // rows per block in fallback fused kernel

typedef int int4v __attribute__((ext_vector_type(4)));

// ---------------------------------------------------------------------------
// Prep — 385 blocks: W bitpack + i8 frag files + thresholds + wfc.
// ---------------------------------------------------------------------------
__global__ __launch_bounds__(256) void bnn_prep(
    const float* __restrict__ w1, const float* __restrict__ b1, const float* __restrict__ g1,
    const float* __restrict__ be1, const float* __restrict__ m1, const float* __restrict__ v1,
    const float* __restrict__ w2, const float* __restrict__ b2, const float* __restrict__ g2,
    const float* __restrict__ be2, const float* __restrict__ m2, const float* __restrict__ v2,
    const float* __restrict__ w3, const float* __restrict__ b3, const float* __restrict__ g3,
    const float* __restrict__ be3, const float* __restrict__ m3, const float* __restrict__ v3,
    const float* __restrict__ wfc,
    uint32_t* __restrict__ ws)
{
    const int blk  = blockIdx.x;
    const int t    = threadIdx.x;
    const int lane = t & 63;
    const int wv   = t >> 6;

    if (blk < 384) {
        const int gid = blk * 256 + t;      // 0..98303
        const int l   = gid >> 15;          // layer 0..2 (32768 words each)
        const int rem = gid & 32767;
        const int o   = rem >> 5;           // channel
        const int k32 = rem & 31;           // word within channel
        const float *w, *bb, *g, *be, *m, *v;
        int K; uint32_t *Wp, *Fl; int *T, *Cdl;
        if (l == 0)      { w=w1; bb=b1; g=g1; be=be1; m=m1; v=v1; K=784;
                           Wp = ws + OFF_W1/4; Fl = ws + OFF_F1/4;
                           T = (int*)(ws + OFF_T1/4); Cdl = (int*)(ws + OFF_C1/4); }
        else if (l == 1) { w=w2; bb=b2; g=g2; be=be2; m=m2; v=v2; K=1024;
                           Wp = ws + OFF_W2/4; Fl = ws + OFF_F2/4;
                           T = (int*)(ws + OFF_T2/4); Cdl = (int*)(ws + OFF_C2/4); }
        else             { w=w3; bb=b3; g=g3; be=be3; m=m3; v=v3; K=1024;
                           Wp = ws + OFF_W3/4; Fl = ws + OFF_F3/4;
                           T = (int*)(ws + OFF_T3/4); Cdl = (int*)(ws + OFF_C3/4); }

        const int base = 32 * k32;
        uint32_t bits = 0;
        double s = 0.0;
        if (base < K) {
            const float4* p = (const float4*)(w + (size_t)o * K + base);
            const int n4 = (K - base >= 32) ? 8 : 4;   // K=784, k32=24 -> 16 elems
            for (int i = 0; i < n4; ++i) {
                float4 q = p[i];
                bits |= (q.x >= 0.0f) ? (1u << (4*i + 0)) : 0u;
                bits |= (q.y >= 0.0f) ? (1u << (4*i + 1)) : 0u;
                bits |= (q.z >= 0.0f) ? (1u << (4*i + 2)) : 0u;
                bits |= (q.w >= 0.0f) ? (1u << (4*i + 3)) : 0u;
                s += fabs((double)q.x) + fabs((double)q.y)
                   + fabs((double)q.z) + fabs((double)q.w);
            }
        }
        // half-wave (32-lane) xor tree: all lanes of the half get channel sum
        #pragma unroll
        for (int mask = 1; mask <= 16; mask <<= 1)
            s += __shfl_xor(s, mask, 64);
        if (k32 == 0) {
            double scale = s / (double)K;                        // mean|w| > 0
            double r = (double)g[o] / sqrt((double)v[o] + 1e-5); // > 0
            double tt = (((double)m[o] - (double)bb[o]) * r - (double)be[o]) / (scale * r);
            double C  = ceil(tt);                                // act=+1 iff dot >= C
            double Cc = fmax(fmin(C, 100000.0), -100000.0);
            Cdl[o] = (int)Cc;
            double Td = floor(((double)K - C) * 0.5);
            Td = fmax(fmin(Td, 100000.0), -1.0);
            T[o] = (int)Td;
        }
        Wp[(size_t)o * 32 + k32] = bits;                          // bitpacked

        // i8 fragment bytes: 32 bits -> two 16-byte groups in frag order.
        const int nt = o >> 4;
        #pragma unroll
        for (int g2i = 0; g2i < 2; ++g2i) {
            const int kg = base + g2i * 16;
            const int kt = kg >> 6;
            const int lane16 = (o & 15) | (((kg >> 4) & 3) << 4);
            uint32_t fb[4];
            #pragma unroll
            for (int wd = 0; wd < 4; ++wd) {
                uint32_t vv = 0;
                #pragma unroll
                for (int bj = 0; bj < 4; ++bj) {
                    const int idx = g2i*16 + wd*4 + bj;
                    const int kk  = base + idx;
                    uint32_t byte = (kk < K) ? (((bits >> idx) & 1u) ? 0x01u : 0xFFu) : 0x00u;
                    vv |= byte << (8*bj);
                }
                fb[wd] = vv;
            }
            uint32_t* dst = Fl + (size_t)((nt*16 + kt) * 256 + lane16 * 4);
            *(uint4*)dst = *(uint4*)fb;
        }
    } else {
        // wfc: 320 words (10 ch x 32); thread t does word t and (t<64) t+256
        uint32_t* Wp  = ws + OFF_WFC/4;
        uint32_t* Ffc = ws + OFF_FFC/4;
        double s = 0.0;
        #pragma unroll
        for (int part = 0; part < 2; ++part) {
            const int tt_ = t + part * 256;
            if (part == 1 && t >= 64) break;
            const int o = tt_ >> 5, k32 = tt_ & 31;
            const int base = 32 * k32;
            const float4* p = (const float4*)(wfc + o * 1024 + base);
            uint32_t bits = 0;
            #pragma unroll
            for (int i = 0; i < 8; ++i) {
                float4 q = p[i];
                bits |= (q.x >= 0.0f) ? (1u << (4*i + 0)) : 0u;
                bits |= (q.y >= 0.0f) ? (1u << (4*i + 1)) : 0u;
                bits |= (q.z >= 0.0f) ? (1u << (4*i + 2)) : 0u;
                bits |= (q.w >= 0.0f) ? (1u << (4*i + 3)) : 0u;
                s += fabs((double)q.x) + fabs((double)q.y)
                   + fabs((double)q.z) + fabs((double)q.w);
            }
            Wp[tt_] = bits;
            #pragma unroll
            for (int g2i = 0; g2i < 2; ++g2i) {
                const int kg = base + g2i * 16;
                const int kt = kg >> 6;
                const int lane16 = (o & 15) | (((kg >> 4) & 3) << 4);
                uint32_t fb[4];
                #pragma unroll
                for (int wd = 0; wd < 4; ++wd) {
                    uint32_t vv = 0;
                    #pragma unroll
                    for (int bj = 0; bj < 4; ++bj) {
                        const int idx = g2i*16 + wd*4 + bj;
                        vv |= (((bits >> idx) & 1u) ? 0x01u : 0xFFu) << (8*bj);
                    }
                    fb[wd] = vv;
                }
                *(uint4*)(Ffc + (size_t)(kt * 256 + lane16 * 4)) = *(uint4*)fb;
            }
        }
        __shared__ double red[4];
        #pragma unroll
        for (int off = 32; off > 0; off >>= 1) s += __shfl_down(s, off, 64);
        if (lane == 0) red[wv] = s;
        __syncthreads();
        if (t == 0)
            *(double*)(ws + OFF_SFC/4) = (red[0] + red[1] + red[2] + red[3]) / 10240.0;
    }
}

// ---------------------------------------------------------------------------
// v15/R16 (proven 164.7us): per-layer MFMA GEMM, BM=64 x BN=256, grid 512,
// XCD-aware swizzle: xcd=bid&7 owns rows [xcd*1024,(xcd+1)*1024) with all 4
// cg quadrants in every layer -> A-tiles fetched by exactly one XCD, act
// row-bands (1 MB/XCD) stay resident in the 4 MB per-XCD L2 across
// dispatches, B (1 MB file) L2-local per XCD. R17's cooperative fusion is
// DROPPED: hipLaunchCooperativeKernel under the harness's hipGraph capture
// is the prime suspect for two consecutive container failures.
// ---------------------------------------------------------------------------
template<bool FIRST>
__global__ __launch_bounds__(512) void bnn_layer_mfma(
    const float*   __restrict__ x,       // used when FIRST
    const uint8_t* __restrict__ actIn,   // used when !FIRST
    const uint8_t* __restrict__ Wfrag,   // 1 MB fragment file
    const int*     __restrict__ Cdot,    // 1024 thresholds
    uint8_t* __restrict__ actOut)        // [8192][1024] i8
{
    __shared__ uint8_t At[64 * 1024];
    const int t    = threadIdx.x;
    const int lane = t & 63;
    const int wv   = t >> 6;            // 0..7
    const int xcd  = blockIdx.x & 7;
    const int idx  = blockIdx.x >> 3;   // 0..63
    const int rg   = xcd * 16 + (idx >> 2);   // 0..127
    const int cgq  = idx & 3;                 // 0..3
    const int row0 = rg * 64;

    if (FIRST) {
        // stage from x: 64 rows x 256 u32 words; w<196 packs 4 floats, else pad.
        #pragma unroll
        for (int i = 0; i < 32; ++i) {
            const int id  = t + i * 512;     // 0..16383
            const int row = id >> 8;         // 0..63
            const int w   = id & 255;        // u32 word in row
            uint32_t wval = 0;
            if (w < 196) {
                const float4 q = *(const float4*)(x + (size_t)(row0 + row) * 784 + 4 * w);
                wval  = ((q.x >= 0.5f) ? 0x01u : 0xFFu);
                wval |= ((q.y >= 0.5f) ? 0x01u : 0xFFu) << 8;
                wval |= ((q.z >= 0.5f) ? 0x01u : 0xFFu) << 16;
                wval |= ((q.w >= 0.5f) ? 0x01u : 0xFFu) << 24;
            }
            *(uint32_t*)(At + row * 1024 + ((4 * w) ^ ((row & 7) << 4))) = wval;
        }
    } else {
        // stage A tile (64 KB): 4096 16-B chunks, thread does 8, coalesced.
        #pragma unroll
        for (int i = 0; i < 8; ++i) {
            const int id  = t + i * 512;     // 0..4095
            const int row = id >> 6;
            const int ks  = id & 63;
            uint4 v = *(const uint4*)(actIn + (size_t)(row0 + row) * 1024 + ks * 16);
            *(uint4*)(At + row * 1024 + ((ks * 16) ^ ((row & 7) << 4))) = v;
        }
    }
    __syncthreads();

    const int col = lane & 15;
    const int lg  = lane >> 4;          // 0..3
    const int nq  = cgq * 16 + wv * 2;  // first of this wave's 2 n-tiles (0..63)

    int4v acc[4][2];
    #pragma unroll
    for (int m = 0; m < 4; ++m)
        #pragma unroll
        for (int j = 0; j < 2; ++j)
            acc[m][j] = (int4v){0, 0, 0, 0};

    // B double buffer, 1 kt deep (kt parity static after full unroll).
    int4v bq[2][2];
    #pragma unroll
    for (int j = 0; j < 2; ++j)
        bq[0][j] = *(const int4v*)(Wfrag + ((size_t)((nq + j) * 16) << 10) + lane * 16);

    #pragma unroll
    for (int kt = 0; kt < 16; ++kt) {
        const int cb = kt & 1, nb = cb ^ 1;
        if (kt < 15) {
            #pragma unroll
            for (int j = 0; j < 2; ++j)
                bq[nb][j] = *(const int4v*)(Wfrag + ((size_t)((nq + j) * 16 + kt + 1) << 10) + lane * 16);
        }
        const int k0 = kt * 64 + lg * 16;
        int4v a[4];
        #pragma unroll
        for (int m = 0; m < 4; ++m)
            a[m] = *(const int4v*)(At + (m * 16 + col) * 1024 + (k0 ^ ((col & 7) << 4)));
        #pragma unroll
        for (int m = 0; m < 4; ++m)
            #pragma unroll
            for (int j = 0; j < 2; ++j)
                acc[m][j] = __builtin_amdgcn_mfma_i32_16x16x64_i8(a[m], bq[cb][j], acc[m][j], 0, 0, 0);
    }

    // ---- epilogue: threshold -> i8 act bytes, plain row-major global store.
    #pragma unroll
    for (int j = 0; j < 2; ++j) {
        const int ch  = (nq + j) * 16 + col;
        const int thr = Cdot[ch];
        #pragma unroll
        for (int m = 0; m < 4; ++m) {
            #pragma unroll
            for (int reg = 0; reg < 4; ++reg) {
                const int row = row0 + m * 16 + lg * 4 + reg;
                actOut[(size_t)row * 1024 + ch] =
                    (acc[m][j][reg] >= thr) ? (uint8_t)0x01 : (uint8_t)0xFF;
            }
        }
    }
}

// ---------------------------------------------------------------------------
// FC: one wave per 32 rows; same XCD-local row-band mapping.
// ---------------------------------------------------------------------------
__global__ __launch_bounds__(64) void bnn_fc_mfma(
    const uint8_t* __restrict__ actIn,
    const uint32_t* __restrict__ ws,
    const float* __restrict__ bfc,
    float* __restrict__ out)
{
    const int lane = threadIdx.x;
    const int col  = lane & 15;
    const int lg   = lane >> 4;
    const int row0 = (blockIdx.x & 7) * 1024 + (blockIdx.x >> 3) * 32;
    const uint8_t* Bf = (const uint8_t*)ws + OFF_FFC;

    int4v acc[2];
    acc[0] = (int4v){0, 0, 0, 0};
    acc[1] = (int4v){0, 0, 0, 0};

    #pragma unroll
    for (int kt = 0; kt < 16; ++kt) {
        int4v b = *(const int4v*)(Bf + ((size_t)kt << 10) + lane * 16);
        #pragma unroll
        for (int m = 0; m < 2; ++m) {
            int4v a = *(const int4v*)(actIn + (size_t)(row0 + m * 16 + col) * 1024 + kt * 64 + lg * 16);
            acc[m] = __builtin_amdgcn_mfma_i32_16x16x64_i8(a, b, acc[m], 0, 0, 0);
        }
    }
    if (col < 10) {
        const float sfc = (float)(*(const double*)(ws + OFF_SFC/4));
        const float bb  = bfc[col];
        #pragma unroll
        for (int m = 0; m < 2; ++m)
            #pragma unroll
            for (int reg = 0; reg < 4; ++reg)
                out[(size_t)(row0 + m * 16 + lg * 4 + reg) * 10 + col] = (float)acc[m][reg] * sfc + bb;
    }
}

// ---------------------------------------------------------------------------
// FALLBACK fused (LDS popcount version) — used only if ws too small.
// ---------------------------------------------------------------------------
__global__ __launch_bounds__(512) void bnn_fused_lds(
    const float* __restrict__ x,
    const uint32_t* __restrict__ ws,
    const float* __restrict__ bfc,
    float* __restrict__ out)
{
    __shared__ alignas(16) uint32_t bufA[RWS][32];
    __shared__ alignas(16) uint32_t bufB[RWS][32];
    const int t    = threadIdx.x;
    const int lane = t & 63;
    const int wv   = t >> 6;
    const int row0 = blockIdx.x * RWS;

    #pragma unroll
    for (int rr = 0; rr < 2; ++rr) {
        const int r = wv + 8 * rr;
        const float* xr = x + (size_t)(row0 + r) * 784;
        #pragma unroll
        for (int k = 0; k < 13; ++k) {
            const int idx = k * 64 + lane;
            const bool bit = (idx < 784) && (xr[idx] >= 0.5f);
            unsigned long long m = __ballot(bit);
            if (lane == 0) *(uint64_t*)(&bufA[r][2 * k]) = m;
        }
        if (lane == 0) {
            *(uint64_t*)(&bufA[r][26]) = 0ull;
            *(uint64_t*)(&bufA[r][28]) = 0ull;
            *(uint64_t*)(&bufA[r][30]) = 0ull;
        }
    }
    __syncthreads();

    const uint32_t* Wbase[3] = { ws + OFF_W1/4, ws + OFF_W2/4, ws + OFF_W3/4 };
    const int*      Tbase[3] = { (const int*)(ws + OFF_T1/4), (const int*)(ws + OFF_T2/4), (const int*)(ws + OFF_T3/4) };

    uint32_t (*cur)[32] = bufA;
    uint32_t (*nxt)[32] = bufB;
    const int c0 = t, c1 = t + 512;

    for (int l = 0; l < 3; ++l) {
        uint32_t W0[32], W1[32];
        {
            const uint4* p0 = (const uint4*)(Wbase[l] + (size_t)c0 * 32);
            const uint4* p1 = (const uint4*)(Wbase[l] + (size_t)c1 * 32);
            #pragma unroll
            for (int i = 0; i < 8; ++i) { ((uint4*)W0)[i] = p0[i]; ((uint4*)W1)[i] = p1[i]; }
        }
        const int T0 = Tbase[l][c0];
        const int T1 = Tbase[l][c1];

        for (int r = 0; r < RWS; ++r) {
            uint32_t A[32];
            #pragma unroll
            for (int i = 0; i < 8; ++i) ((uint4*)A)[i] = ((const uint4*)cur[r])[i];
            int pa = 0, pb = 0, pc = 0, pd = 0;
            #pragma unroll
            for (int i = 0; i < 16; ++i) {
                pa += __popc(A[i]      ^ W0[i]);
                pb += __popc(A[i + 16] ^ W0[i + 16]);
                pc += __popc(A[i]      ^ W1[i]);
                pd += __popc(A[i + 16] ^ W1[i + 16]);
            }
            unsigned long long m0 = __ballot((pa + pb) <= T0);
            unsigned long long m1 = __ballot((pc + pd) <= T1);
            if (lane == 0) {
                *(uint64_t*)(&nxt[r][2 * wv])      = m0;
                *(uint64_t*)(&nxt[r][16 + 2 * wv]) = m1;
            }
        }
        __syncthreads();
        uint32_t (*tmp)[32] = cur; cur = nxt; nxt = tmp;
    }

    if (t < RWS * 10) {
        const float sfc = (float)(*(const double*)(ws + OFF_SFC/4));
        const uint32_t* Wfc = ws + OFF_WFC/4;
        const int r = t / 10, ch = t % 10;
        const uint32_t* wrow = Wfc + ch * 32;
        int p = 0;
        #pragma unroll
        for (int i = 0; i < 32; ++i) p += __popc(cur[r][i] ^ wrow[i]);
        out[(size_t)(row0 + r) * 10 + ch] = (float)(1024 - 2 * p) * sfc + bfc[ch];
    }
}

extern "C" void kernel_launch(void* const* d_in, const int* in_sizes, int n_in,
                              void* d_out, int out_size, void* d_ws, size_t ws_size,
                              hipStream_t stream) {
    const float* x   = (const float*)d_in[0];
    const float* w1  = (const float*)d_in[1];
    const float* b1  = (const float*)d_in[2];
    const float* g1  = (const float*)d_in[3];
    const float* be1 = (const float*)d_in[4];
    const float* m1  = (const float*)d_in[5];
    const float* v1  = (const float*)d_in[6];
    const float* w2  = (const float*)d_in[7];
    const float* b2  = (const float*)d_in[8];
    const float* g2  = (const float*)d_in[9];
    const float* be2 = (const float*)d_in[10];
    const float* m2  = (const float*)d_in[11];
    const float* v2  = (const float*)d_in[12];
    const float* w3  = (const float*)d_in[13];
    const float* b3  = (const float*)d_in[14];
    const float* g3  = (const float*)d_in[15];
    const float* be3 = (const float*)d_in[16];
    const float* m3  = (const float*)d_in[17];
    const float* v3  = (const float*)d_in[18];
    const float* wfc = (const float*)d_in[19];
    const float* bfc = (const float*)d_in[20];
    uint32_t* ws = (uint32_t*)d_ws;
    float* out = (float*)d_out;

    // prep: weights only (x-pack folded into layer 1)
    bnn_prep<<<385, 256, 0, stream>>>(
        w1, b1, g1, be1, m1, v1,
        w2, b2, g2, be2, m2, v2,
        w3, b3, g3, be3, m3, v3,
        wfc, ws);

    if (ws_size >= (size_t)WS_NEED_V12) {
        uint8_t* S0 = (uint8_t*)ws + OFF_S0;
        uint8_t* S1 = (uint8_t*)ws + OFF_S1;
        const uint8_t* F1 = (const uint8_t*)ws + OFF_F1;
        const uint8_t* F2 = (const uint8_t*)ws + OFF_F2;
        const uint8_t* F3 = (const uint8_t*)ws + OFF_F3;
        bnn_layer_mfma<true ><<<512, 512, 0, stream>>>(x, nullptr, F1, (const int*)(ws + OFF_C1/4), S1);
        bnn_layer_mfma<false><<<512, 512, 0, stream>>>(x, S1,      F2, (const int*)(ws + OFF_C2/4), S0);
        bnn_layer_mfma<false><<<512, 512, 0, stream>>>(x, S0,      F3, (const int*)(ws + OFF_C3/4), S1);
        bnn_fc_mfma<<<256, 64, 0, stream>>>(S1, ws, bfc, out);
    } else {
        bnn_fused_lds<<<8192 / RWS, 512, 0, stream>>>(x, ws, bfc, out);
    }
}